// Round 5
// baseline (79.091 us; speedup 1.0000x reference)
//
#include <hip/hip_runtime.h>

#define H 512
#define W 512
#define NIMG 8
#define SW 513                    // SAT dimension (H+1)
#define SAT_PER (SW * SW)
#define NBAND 16
#define BROWS 32                  // rows per band (NBAND*BROWS == H)

// k_main tiling
#define TW 64                     // tile width  (pixels)
#define TH 16                     // tile height (pixels)
#define LR 77                     // staged SAT rows  (TH + 61)
#define LC 126                    // staged SAT cols  (TW + 62), also LDS stride

// zero-padded global load ('SAME' conv padding)
__device__ __forceinline__ float ldz(const float* __restrict__ p, int y, int x) {
    return ((unsigned)y < (unsigned)H && (unsigned)x < (unsigned)W) ? p[y * W + x] : 0.0f;
}

// Sobel (cross-correlation, matches lax.conv)
__device__ __forceinline__ void sobel_g(const float* __restrict__ p, int y, int x,
                                        float& gx, float& gy) {
    float a00 = ldz(p, y - 1, x - 1), a01 = ldz(p, y - 1, x), a02 = ldz(p, y - 1, x + 1);
    float a10 = ldz(p, y,     x - 1),                          a12 = ldz(p, y,     x + 1);
    float a20 = ldz(p, y + 1, x - 1), a21 = ldz(p, y + 1, x), a22 = ldz(p, y + 1, x + 1);
    gx = (a02 - a00) + 2.0f * (a12 - a10) + (a22 - a20);
    gy = (a20 - a00) + 2.0f * (a21 - a01) + (a22 - a02);
}

// ---- kernel 1: energy + row prefix + band-local column prefix ------------
// Block = one 32-row band of one (image, map). Writes B rows 1+32b .. 32(b+1):
// B[y][x] = sum over rows within the band (<= y) of row-prefix R.
__global__ __launch_bounds__(512) void k_rowband(const float* __restrict__ v,
                                                 const float* __restrict__ i_,
                                                 float* __restrict__ B) {
    const int band = blockIdx.x;
    const int n = blockIdx.y;
    const int m = blockIdx.z;
    const float* src = (m == 0 ? v : i_) + (size_t)n * (H * W);
    float* Bm = B + (size_t)(n * 2 + m) * SAT_PER;

    __shared__ float tile[BROWS][SW];          // 32*513*4 = 65.7 KB

    const int lane = threadIdx.x & 63;
    const int wv   = threadIdx.x >> 6;         // 0..7
    const int x0   = lane * 8;

    #pragma unroll
    for (int k = 0; k < 4; ++k) {
        const int j = k * 8 + wv;              // row within band
        const int y = band * BROWS + j;
        // 3x10 neighborhood covering 8 consecutive sobels
        float a[10], b[10], c[10];
        #pragma unroll
        for (int q = 0; q < 10; ++q) {
            int xx = x0 - 1 + q;
            a[q] = ldz(src, y - 1, xx);
            b[q] = ldz(src, y,     xx);
            c[q] = ldz(src, y + 1, xx);
        }
        float e[8];
        #pragma unroll
        for (int q = 0; q < 8; ++q) {
            float gx = (a[q + 2] - a[q]) + 2.0f * (b[q + 2] - b[q]) + (c[q + 2] - c[q]);
            float gy = (c[q] - a[q]) + 2.0f * (c[q + 1] - a[q + 1]) + (c[q + 2] - a[q + 2]);
            e[q] = gx * gx + gy * gy;
        }
        #pragma unroll
        for (int q = 1; q < 8; ++q) e[q] += e[q - 1];   // in-lane inclusive prefix
        const float tot = e[7];
        float s = tot;                                   // wave inclusive scan of totals
        #pragma unroll
        for (int off = 1; off < 64; off <<= 1) {
            float t = __shfl_up(s, off, 64);
            if (lane >= off) s += t;
        }
        const float excl = s - tot;
        if (lane == 0) tile[j][0] = 0.0f;
        #pragma unroll
        for (int q = 0; q < 8; ++q) tile[j][1 + x0 + q] = e[q] + excl;
    }
    __syncthreads();

    // band-local column prefix (inclusive) over the 32 rows
    for (int c2 = threadIdx.x; c2 < SW; c2 += 512) {
        float run = 0.0f;
        #pragma unroll
        for (int j = 0; j < BROWS; ++j) {
            run += tile[j][c2];
            tile[j][c2] = run;
        }
    }
    __syncthreads();

    // coalesced writeout: SAT rows 1 + band*32 + j
    for (int j = 0; j < BROWS; ++j)
        for (int c2 = threadIdx.x; c2 < SW; c2 += 512)
            Bm[(size_t)(1 + band * BROWS + j) * SW + c2] = tile[j][c2];
}

// ---- kernel 2: exclusive scan of band boundary rows -> C ------------------
// C[map][b][c] = sum over b'<b of B[map][32*(b'+1)][c]
__global__ __launch_bounds__(256) void k_bandscan(const float* __restrict__ B,
                                                  float* __restrict__ C) {
    const int c = blockIdx.x * 256 + threadIdx.x;
    if (c >= SW) return;
    const int map = blockIdx.y;
    const float* Bm = B + (size_t)map * SAT_PER;
    float* Cm = C + (size_t)map * NBAND * SW;
    float run = 0.0f;
    #pragma unroll
    for (int b = 0; b < NBAND; ++b) {
        Cm[(size_t)b * SW + c] = run;
        run += Bm[(size_t)((b + 1) * BROWS) * SW + c];
    }
}

// ---- kernel 3: LDS-staged SAT reconstruction + fused residual -------------
__global__ __launch_bounds__(1024, 8) void k_main(const float* __restrict__ v,
                                                  const float* __restrict__ i_,
                                                  const float* __restrict__ img,
                                                  const float* __restrict__ B,
                                                  const float* __restrict__ C,
                                                  double* __restrict__ partials) {
    __shared__ float2 S2[LR * LC];             // {Sv, Si} interleaved, 77.6 KB

    const int bid = blockIdx.x;
    const int n  = bid & 7;                    // image -> XCD round-robin
    const int t  = bid >> 3;                   // 0..255
    const int tx = t & 7, ty = t >> 3;         // tx<8, ty<32
    const int oy = ty * TH - 30, ox = tx * TW - 30;

    const float* pv = v   + (size_t)n * (H * W);
    const float* pi = i_  + (size_t)n * (H * W);
    const float* pf = img + (size_t)n * (H * W);
    const float* Bv = B + (size_t)(n * 2 + 0) * SAT_PER;
    const float* Bi = B + (size_t)(n * 2 + 1) * SAT_PER;
    const float* Cv = C + (size_t)(n * 2 + 0) * NBAND * SW;
    const float* Ci = C + (size_t)(n * 2 + 1) * NBAND * SW;

    // stage reconstructed SAT: S(yy,xx) = yy==0 ? 0 : B[yy][xx] + C[(yy-1)>>5][xx]
    {
        const int c0 = threadIdx.x & 127;
        const int r0 = threadIdx.x >> 7;       // 0..7
        if (c0 < LC) {
            const int xx = ox + c0;
            const bool okx = (unsigned)xx <= (unsigned)W;   // xx in [0,512]
            for (int r = r0; r < LR; r += 8) {
                const int yy = oy + r;
                float sv = 0.0f, si = 0.0f;
                if (okx && (unsigned)(yy - 1) < (unsigned)H) {  // yy in [1,512]
                    const int b = (yy - 1) >> 5;
                    const size_t o1 = (size_t)yy * SW + xx;
                    const size_t o2 = (size_t)b * SW + xx;
                    sv = Bv[o1] + Cv[o2];
                    si = Bi[o1] + Ci[o2];
                }
                S2[r * LC + c0] = make_float2(sv, si);
            }
        }
    }
    __syncthreads();

    // one pixel per thread
    const int lx = threadIdx.x & 63;
    const int ly = threadIdx.x >> 6;           // 0..15
    const int x = tx * TW + lx;
    const int y = ty * TH + ly;

    float gvx, gvy, gix, giy, gfx, gfy;
    sobel_g(pv, y, x, gvx, gvy);
    sobel_g(pi, y, x, gix, giy);
    sobel_g(pf, y, x, gfx, gfy);

    const int   radii[5] = {1, 3, 7, 15, 30};
    const float iw2[5]   = {1.0f / 9.0f, 1.0f / 49.0f, 1.0f / 225.0f,
                            1.0f / 961.0f, 1.0f / 3721.0f};

    float acc = 0.0f;
    #pragma unroll
    for (int k = 0; k < 5; ++k) {
        const int r = radii[k];
        const int ly0 = max(y - r, 0) - oy, ly1 = min(y + r + 1, H) - oy;
        const int lx0 = max(x - r, 0) - ox, lx1 = min(x + r + 1, W) - ox;
        float2 q11 = S2[ly1 * LC + lx1];
        float2 q01 = S2[ly0 * LC + lx1];
        float2 q10 = S2[ly1 * LC + lx0];
        float2 q00 = S2[ly0 * LC + lx0];
        float sv = q11.x - q01.x - q10.x + q00.x;
        float si = q11.y - q01.y - q10.y + q00.y;
        float ev = sv * iw2[k];
        float ei = si * iw2[k];
        float wtt = ev / (ev + ei + 1e-8f);
        float txv = gix + wtt * (gvx - gix);
        float tyv = giy + wtt * (gvy - giy);
        float dx = gfx - txv, dy = gfy - tyv;
        acc += dx * dx + dy * dy;
    }

    // block reduction (f64, deterministic)
    double a = (double)acc;
    const int lane = threadIdx.x & 63, wid = threadIdx.x >> 6;
    #pragma unroll
    for (int off = 32; off > 0; off >>= 1) a += __shfl_down(a, off, 64);
    __shared__ double red[16];
    if (lane == 0) red[wid] = a;
    __syncthreads();
    if (threadIdx.x == 0) {
        double s = 0.0;
        #pragma unroll
        for (int q = 0; q < 16; ++q) s += red[q];
        partials[bid] = s;
    }
}

// ---- kernel 4: final reduce ------------------------------------------------
__global__ __launch_bounds__(256) void k_reduce(const double* __restrict__ partials,
                                                int np, float* __restrict__ out) {
    __shared__ double red[256];
    double s = 0.0;
    for (int idx = threadIdx.x; idx < np; idx += 256) s += partials[idx];
    red[threadIdx.x] = s;
    __syncthreads();
    #pragma unroll
    for (int t = 128; t > 0; t >>= 1) {
        if (threadIdx.x < t) red[threadIdx.x] += red[threadIdx.x + t];
        __syncthreads();
    }
    if (threadIdx.x == 0)
        out[0] = (float)(red[0] / (double)((size_t)NIMG * H * W));
}

// ---- launch -----------------------------------------------------------------

extern "C" void kernel_launch(void* const* d_in, const int* in_sizes, int n_in,
                              void* d_out, int out_size, void* d_ws, size_t ws_size,
                              hipStream_t stream) {
    const float* v   = (const float*)d_in[0];
    const float* i_  = (const float*)d_in[1];
    const float* img = (const float*)d_in[2];
    float* out = (float*)d_out;

    float* B         = (float*)d_ws;                               // 16 * 513*513 f32 = 16.8 MB
    float* C         = B + (size_t)16 * SAT_PER;                   // 16 * 16 * 513 f32
    double* partials = (double*)(C + (size_t)16 * NBAND * SW);     // 2048 f64

    k_rowband<<<dim3(NBAND, NIMG, 2), dim3(512), 0, stream>>>(v, i_, B);
    k_bandscan<<<dim3(3, 16), dim3(256), 0, stream>>>(B, C);
    k_main<<<dim3(2048), dim3(1024), 0, stream>>>(v, i_, img, B, C, partials);
    k_reduce<<<dim3(1), dim3(256), 0, stream>>>(partials, 2048, out);
}

// Round 6
// 74.000 us; speedup vs baseline: 1.0688x; 1.0688x over previous
//
#include <hip/hip_runtime.h>

#define H 512
#define W 512
#define NIMG 8
#define SW 513                    // SAT logical dimension (H+1)
#define SAT_PER (SW * SW)
#define NBAND 16
#define BROWS 32                  // rows per band (NBAND*BROWS == H)

#define PS 576                    // padded SAT stride (32 + 513 + 31)
#define PP (PS * PS)              // padded plane size
#define PADY 32
#define PADX 32

typedef float f4 __attribute__((ext_vector_type(4)));

// unaligned-tolerant float4 load (4B alignment)
__device__ __forceinline__ f4 ld4(const float* p) {
    f4 r;
    __builtin_memcpy(&r, p, 16);
    return r;
}

// zero-padded global load ('SAME' conv padding)
__device__ __forceinline__ float ldz(const float* __restrict__ p, int y, int x) {
    return ((unsigned)y < (unsigned)H && (unsigned)x < (unsigned)W) ? p[y * W + x] : 0.0f;
}

// ---- kernel 1: energy + row prefix + band-local column prefix ------------
__global__ __launch_bounds__(512) void k_rowband(const float* __restrict__ v,
                                                 const float* __restrict__ i_,
                                                 float* __restrict__ B) {
    const int band = blockIdx.x;
    const int n = blockIdx.y;
    const int m = blockIdx.z;
    const float* src = (m == 0 ? v : i_) + (size_t)n * (H * W);
    float* Bm = B + (size_t)(n * 2 + m) * SAT_PER;

    __shared__ float tile[BROWS][SW];          // 65.7 KB

    const int lane = threadIdx.x & 63;
    const int wv   = threadIdx.x >> 6;         // 0..7
    const int x0   = lane * 8;

    #pragma unroll
    for (int k = 0; k < 4; ++k) {
        const int j = k * 8 + wv;              // row within band
        const int y = band * BROWS + j;
        float a[10], b[10], c[10];
        #pragma unroll
        for (int q = 0; q < 10; ++q) {
            int xx = x0 - 1 + q;
            a[q] = ldz(src, y - 1, xx);
            b[q] = ldz(src, y,     xx);
            c[q] = ldz(src, y + 1, xx);
        }
        float e[8];
        #pragma unroll
        for (int q = 0; q < 8; ++q) {
            float gx = (a[q + 2] - a[q]) + 2.0f * (b[q + 2] - b[q]) + (c[q + 2] - c[q]);
            float gy = (c[q] - a[q]) + 2.0f * (c[q + 1] - a[q + 1]) + (c[q + 2] - a[q + 2]);
            e[q] = gx * gx + gy * gy;
        }
        #pragma unroll
        for (int q = 1; q < 8; ++q) e[q] += e[q - 1];
        const float tot = e[7];
        float s = tot;
        #pragma unroll
        for (int off = 1; off < 64; off <<= 1) {
            float t = __shfl_up(s, off, 64);
            if (lane >= off) s += t;
        }
        const float excl = s - tot;
        if (lane == 0) tile[j][0] = 0.0f;
        #pragma unroll
        for (int q = 0; q < 8; ++q) tile[j][1 + x0 + q] = e[q] + excl;
    }
    __syncthreads();

    // band-local column prefix (inclusive) over the 32 rows
    for (int c2 = threadIdx.x; c2 < SW; c2 += 512) {
        float run = 0.0f;
        #pragma unroll
        for (int j = 0; j < BROWS; ++j) {
            run += tile[j][c2];
            tile[j][c2] = run;
        }
    }
    __syncthreads();

    for (int j = 0; j < BROWS; ++j)
        for (int c2 = threadIdx.x; c2 < SW; c2 += 512)
            Bm[(size_t)(1 + band * BROWS + j) * SW + c2] = tile[j][c2];
}

// ---- kernel 2: exclusive scan of band boundary rows -> C ------------------
__global__ __launch_bounds__(256) void k_bandscan(const float* __restrict__ B,
                                                  float* __restrict__ C) {
    const int c = blockIdx.x * 256 + threadIdx.x;
    if (c >= SW) return;
    const int map = blockIdx.y;
    const float* Bm = B + (size_t)map * SAT_PER;
    float* Cm = C + (size_t)map * NBAND * SW;
    float run = 0.0f;
    #pragma unroll
    for (int b = 0; b < NBAND; ++b) {
        Cm[(size_t)b * SW + c] = run;
        run += Bm[(size_t)((b + 1) * BROWS) * SW + c];
    }
}

// ---- kernel 3: finalize padded SAT P = B + C with clamp-free padding ------
// P[p][c]: rows p<=32 are zeros (SAT row 0 & top pad); p-32>512 replicates row 512.
// cols c<32 -> x=0 (zero col of SAT); c-32>512 replicates col 512.
__global__ __launch_bounds__(256) void k_finalize(const float* __restrict__ B,
                                                  const float* __restrict__ C,
                                                  float* __restrict__ P) {
    const int p  = blockIdx.x;       // 0..575
    const int mp = blockIdx.y;       // 0..15
    float* dst = P + (size_t)mp * PP + (size_t)p * PS;
    const int ys = p - PADY;
    if (ys <= 0) {
        for (int c = threadIdx.x; c < PS; c += 256) dst[c] = 0.0f;
        return;
    }
    const int y = min(ys, H);
    const int b = (y - 1) >> 5;
    const float* Brow = B + (size_t)mp * SAT_PER + (size_t)y * SW;
    const float* Crow = C + ((size_t)mp * NBAND + b) * SW;
    for (int c = threadIdx.x; c < PS; c += 256) {
        int x = min(max(c - PADX, 0), W);
        dst[c] = Brow[x] + Crow[x];
    }
}

// ---- sobel for 4 consecutive pixels --------------------------------------
__device__ __forceinline__ void sobel4(const float* __restrict__ p, int y, int x4,
                                       bool fast, float gx[4], float gy[4]) {
    float r0[6], r1[6], r2[6];
    if (fast) {
        const float* a = p + (size_t)(y - 1) * W + (x4 - 1);
        #pragma unroll
        for (int q = 0; q < 6; ++q) {
            r0[q] = a[q]; r1[q] = a[W + q]; r2[q] = a[2 * W + q];
        }
    } else {
        #pragma unroll
        for (int q = 0; q < 6; ++q) {
            r0[q] = ldz(p, y - 1, x4 - 1 + q);
            r1[q] = ldz(p, y,     x4 - 1 + q);
            r2[q] = ldz(p, y + 1, x4 - 1 + q);
        }
    }
    #pragma unroll
    for (int q = 0; q < 4; ++q) {
        gx[q] = (r0[q + 2] - r0[q]) + 2.0f * (r1[q + 2] - r1[q]) + (r2[q + 2] - r2[q]);
        gy[q] = (r2[q] - r0[q]) + 2.0f * (r2[q + 1] - r0[q + 1]) + (r2[q + 2] - r0[q + 2]);
    }
}

// ---- kernel 4: fused sobel + clamp-free f4 SAT gather + residual ---------
__global__ __launch_bounds__(256) void k_main(const float* __restrict__ v,
                                              const float* __restrict__ i_,
                                              const float* __restrict__ img,
                                              const float* __restrict__ P,
                                              double* __restrict__ partials) {
    const int bid = blockIdx.x;
    const int n = bid & 7;                     // image -> XCD round-robin
    const int t = bid >> 3;                    // 0..255
    const int tx = t & 3, ty = t >> 2;         // tile: 128 wide x 8 rows
    const int col = threadIdx.x & 31, row = threadIdx.x >> 5;
    const int x4 = tx * 128 + col * 4;
    const int y  = ty * 8 + row;

    const float* pv = v   + (size_t)n * (H * W);
    const float* pi = i_  + (size_t)n * (H * W);
    const float* pf = img + (size_t)n * (H * W);
    const float* Pv = P + (size_t)(n * 2 + 0) * PP;
    const float* Pi = P + (size_t)(n * 2 + 1) * PP;

    float gvx[4], gvy[4], gix[4], giy[4], gfx[4], gfy[4];
    const bool fast = (y >= 1 && y <= H - 2 && x4 >= 4 && x4 <= W - 8);
    sobel4(pv, y, x4, fast, gvx, gvy);
    sobel4(pi, y, x4, fast, gix, giy);
    sobel4(pf, y, x4, fast, gfx, gfy);

    const int   radii[5] = {1, 3, 7, 15, 30};
    const float iw2[5]   = {1.0f / 9.0f, 1.0f / 49.0f, 1.0f / 225.0f,
                            1.0f / 961.0f, 1.0f / 3721.0f};

    float acc = 0.0f;
    #pragma unroll
    for (int k = 0; k < 5; ++k) {
        const int r = radii[k];
        const size_t ro0 = (size_t)(y - r + PADY) * PS;
        const size_t ro1 = (size_t)(y + r + 1 + PADY) * PS;
        const int x0 = x4 - r + PADX;
        const int x1 = x4 + r + 1 + PADX;
        f4 sa = ld4(Pv + ro1 + x1), sb = ld4(Pv + ro0 + x1);
        f4 sc = ld4(Pv + ro1 + x0), sd = ld4(Pv + ro0 + x0);
        f4 ua = ld4(Pi + ro1 + x1), ub = ld4(Pi + ro0 + x1);
        f4 uc = ld4(Pi + ro1 + x0), ud = ld4(Pi + ro0 + x0);
        f4 sv = sa - sb - sc + sd;
        f4 si = ua - ub - uc + ud;
        #pragma unroll
        for (int q = 0; q < 4; ++q) {
            float ev = sv[q] * iw2[k];
            float ei = si[q] * iw2[k];
            float wt = ev / (ev + ei + 1e-8f);
            float txv = gix[q] + wt * (gvx[q] - gix[q]);
            float tyv = giy[q] + wt * (gvy[q] - giy[q]);
            float dx = gfx[q] - txv, dy = gfy[q] - tyv;
            acc += dx * dx + dy * dy;
        }
    }

    // block reduction (f64, deterministic)
    double a = (double)acc;
    const int lane = threadIdx.x & 63, wid = threadIdx.x >> 6;
    #pragma unroll
    for (int off = 32; off > 0; off >>= 1) a += __shfl_down(a, off, 64);
    __shared__ double red[4];
    if (lane == 0) red[wid] = a;
    __syncthreads();
    if (threadIdx.x == 0)
        partials[bid] = red[0] + red[1] + red[2] + red[3];
}

// ---- kernel 5: final reduce ----------------------------------------------
__global__ __launch_bounds__(256) void k_reduce(const double* __restrict__ partials,
                                                int np, float* __restrict__ out) {
    __shared__ double red[256];
    double s = 0.0;
    for (int idx = threadIdx.x; idx < np; idx += 256) s += partials[idx];
    red[threadIdx.x] = s;
    __syncthreads();
    #pragma unroll
    for (int t = 128; t > 0; t >>= 1) {
        if (threadIdx.x < t) red[threadIdx.x] += red[threadIdx.x + t];
        __syncthreads();
    }
    if (threadIdx.x == 0)
        out[0] = (float)(red[0] / (double)((size_t)NIMG * H * W));
}

// ---- launch --------------------------------------------------------------

extern "C" void kernel_launch(void* const* d_in, const int* in_sizes, int n_in,
                              void* d_out, int out_size, void* d_ws, size_t ws_size,
                              hipStream_t stream) {
    const float* v   = (const float*)d_in[0];
    const float* i_  = (const float*)d_in[1];
    const float* img = (const float*)d_in[2];
    float* out = (float*)d_out;

    float* B         = (float*)d_ws;                               // 16 * 513*513 f32 = 16.8 MB
    float* C         = B + (size_t)16 * SAT_PER;                   // 16 * 16 * 513 f32
    float* P         = C + (size_t)16 * NBAND * SW;                // 16 * 576*576 f32 = 21.2 MB
    double* partials = (double*)(P + (size_t)16 * PP);             // 2048 f64

    k_rowband<<<dim3(NBAND, NIMG, 2), dim3(512), 0, stream>>>(v, i_, B);
    k_bandscan<<<dim3(3, 16), dim3(256), 0, stream>>>(B, C);
    k_finalize<<<dim3(PS, 16), dim3(256), 0, stream>>>(B, C, P);
    k_main<<<dim3(2048), dim3(256), 0, stream>>>(v, i_, img, P, partials);
    k_reduce<<<dim3(1), dim3(256), 0, stream>>>(partials, 2048, out);
}